// Round 1
// 1238.195 us; speedup vs baseline: 1.1579x; 1.1579x over previous
//
#include <hip/hip_runtime.h>
#include <cstddef>
#include <cstdint>

// Problem constants (from reference)
constexpr int kB  = 4;
constexpr int kS  = 2048;
constexpr int kH  = 512;
constexpr int kNH = 8;
constexpr int kHD = 64;
constexpr int kM  = kB * kS;        // 8192 rows for the projection GEMMs
constexpr int kK  = 512;            // inner dim for all projection GEMMs

using bf16x8  = __attribute__((ext_vector_type(8))) short;   // 8 bf16 = 4 VGPRs (MFMA A/B frag)
using f32x4   = __attribute__((ext_vector_type(4))) float;   // MFMA C/D frag
using short4v = __attribute__((ext_vector_type(4))) short;

__device__ __forceinline__ unsigned short f32_to_bf16(float f) {
  unsigned int u = __float_as_uint(f);
  u += 0x7FFFu + ((u >> 16) & 1u);                 // round-to-nearest-even
  return (unsigned short)(u >> 16);
}
__device__ __forceinline__ float bf16_to_f32(unsigned short h) {
  return __uint_as_float(((unsigned int)h) << 16);
}
__device__ __forceinline__ void split_bf16(float v, unsigned short& hi,
                                           unsigned short& lo) {
  hi = f32_to_bf16(v);
  lo = f32_to_bf16(v - bf16_to_f32(hi));           // residual, exact subtract
}

#define FMA16(a, b)                                                        \
  do {                                                                     \
    acc[0][0] += a.x * b.x; acc[0][1] += a.x * b.y;                        \
    acc[0][2] += a.x * b.z; acc[0][3] += a.x * b.w;                        \
    acc[1][0] += a.y * b.x; acc[1][1] += a.y * b.y;                        \
    acc[1][2] += a.y * b.z; acc[1][3] += a.y * b.w;                        \
    acc[2][0] += a.z * b.x; acc[2][1] += a.z * b.y;                        \
    acc[2][2] += a.z * b.z; acc[2][3] += a.z * b.w;                        \
    acc[3][0] += a.w * b.x; acc[3][1] += a.w * b.y;                        \
    acc[3][2] += a.w * b.z; acc[3][3] += a.w * b.w;                        \
  } while (0)

// C = A(M,512) * W(512,512)^T + bias, NT GEMM, 64x64 tile, 4x4 per thread.
// MODE 0: store bf16 hi/lo split, head-major [bh][s][d]       (Q,K projections)
// MODE 1: store fp32 row-major out[m*512 + n]                 (output projection)
// MODE 2: store bf16 hi/lo split, TRANSPOSED [bh][d][s]       (V projection)
template <int MODE>
__global__ __launch_bounds__(256) void gemm_nt_bias(
    const float* __restrict__ A, const float* __restrict__ W,
    const float* __restrict__ bias, float* __restrict__ outf,
    unsigned short* __restrict__ out_hi, unsigned short* __restrict__ out_lo)
{
  __shared__ __align__(16) float As[16][68];   // [k][m], padded
  __shared__ __align__(16) float Ws[16][68];   // [k][n], padded

  const int tid  = threadIdx.x;
  const int ty   = tid >> 4;          // 0..15
  const int tx   = tid & 15;          // 0..15
  const int m0   = blockIdx.x * 64;
  const int n0   = blockIdx.y * 64;
  const int lrow = tid >> 2;          // 0..63
  const int lcol = (tid & 3) << 2;    // 0,4,8,12

  float acc[4][4] = {};

  for (int k0 = 0; k0 < kK; k0 += 16) {
    float4 av = *(const float4*)(A + (size_t)(m0 + lrow) * kK + k0 + lcol);
    float4 wv = *(const float4*)(W + (size_t)(n0 + lrow) * kK + k0 + lcol);
    __syncthreads();
    As[lcol + 0][lrow] = av.x; As[lcol + 1][lrow] = av.y;
    As[lcol + 2][lrow] = av.z; As[lcol + 3][lrow] = av.w;
    Ws[lcol + 0][lrow] = wv.x; Ws[lcol + 1][lrow] = wv.y;
    Ws[lcol + 2][lrow] = wv.z; Ws[lcol + 3][lrow] = wv.w;
    __syncthreads();
#pragma unroll
    for (int kk = 0; kk < 16; ++kk) {
      float4 a = *(const float4*)&As[kk][ty << 2];
      float4 b = *(const float4*)&Ws[kk][tx << 2];
      FMA16(a, b);
    }
  }

  float4 bv = *(const float4*)(bias + n0 + (tx << 2));
  const int h = n0 >> 6;              // tile is head-aligned (64 = HD)
#pragma unroll
  for (int i = 0; i < 4; ++i) {
    const int m = m0 + (ty << 2) + i;
    float o[4] = {acc[i][0] + bv.x, acc[i][1] + bv.y,
                  acc[i][2] + bv.z, acc[i][3] + bv.w};
    if (MODE == 1) {
      *(float4*)(outf + (size_t)m * kH + n0 + (tx << 2)) =
          make_float4(o[0], o[1], o[2], o[3]);
    } else {
      const int b = m >> 11;          // m / S
      const int s = m & (kS - 1);
      const int bh = b * kNH + h;
      unsigned short hi[4], lo[4];
#pragma unroll
      for (int j = 0; j < 4; ++j) split_bf16(o[j], hi[j], lo[j]);
      if (MODE == 0) {
        const size_t idx = (((size_t)bh) * kS + s) * kHD + (tx << 2);
        short4v hv = {(short)hi[0], (short)hi[1], (short)hi[2], (short)hi[3]};
        short4v lv = {(short)lo[0], (short)lo[1], (short)lo[2], (short)lo[3]};
        *(short4v*)(out_hi + idx) = hv;
        *(short4v*)(out_lo + idx) = lv;
      } else {                        // MODE 2: V transposed [bh][d][s]
#pragma unroll
        for (int j = 0; j < 4; ++j) {
          const int d = (tx << 2) + j;
          const size_t idx = (((size_t)bh) * kHD + d) * kS + s;
          out_hi[idx] = hi[j];
          out_lo[idx] = lo[j];
        }
      }
    }
  }
}

// scores[bh][i][j] = 0.125 * sum_d Q[bh][i][d]*K[bh][j][d], split-bf16 MFMA.
// 128x128 tile per block, 4 waves in 2x2, each wave 64x64 (4x4 frags of 16x16).
__global__ __launch_bounds__(256, 2) void scores_mfma(
    const unsigned short* __restrict__ Qhi, const unsigned short* __restrict__ Qlo,
    const unsigned short* __restrict__ Khi, const unsigned short* __restrict__ Klo,
    float* __restrict__ attn)
{
  // 4 tiles of [128 rows][64 bf16] = 16 KB each, XOR-swizzled rows -> 64 KB
  __shared__ __align__(16) unsigned short lds[4 * 128 * 64];
  unsigned short* sQh = lds;
  unsigned short* sQl = lds + 8192;
  unsigned short* sKh = lds + 16384;
  unsigned short* sKl = lds + 24576;

  const int tid = threadIdx.x;
  const int i0  = blockIdx.x * 128;
  const int j0  = blockIdx.y * 128;
  const int bh  = blockIdx.z;
  const size_t hbase = (size_t)bh * kS * kHD;

  const char* gq_h = (const char*)(Qhi + hbase + (size_t)i0 * kHD);
  const char* gq_l = (const char*)(Qlo + hbase + (size_t)i0 * kHD);
  const char* gk_h = (const char*)(Khi + hbase + (size_t)j0 * kHD);
  const char* gk_l = (const char*)(Klo + hbase + (size_t)j0 * kHD);

  // stage: each tile is 16 KB contiguous = 1024 x 16B chunks; 4 per thread
#pragma unroll
  for (int it = 0; it < 4; ++it) {
    const int c   = tid + it * 256;          // 0..1023
    const int row = c >> 3;                  // 0..127
    const int bo  = (c & 7) << 4;            // byte col in row
    const int so  = bo ^ ((row & 7) << 4);   // swizzled
    const int go  = row * 128 + bo;
    const int lo_ = row * 128 + so;
    *(float4*)((char*)sQh + lo_) = *(const float4*)(gq_h + go);
    *(float4*)((char*)sQl + lo_) = *(const float4*)(gq_l + go);
    *(float4*)((char*)sKh + lo_) = *(const float4*)(gk_h + go);
    *(float4*)((char*)sKl + lo_) = *(const float4*)(gk_l + go);
  }
  __syncthreads();

  const int wid  = tid >> 6;
  const int lane = tid & 63;
  const int wr   = wid >> 1, wc = wid & 1;
  const int lr   = lane & 15;                // frag row/col within 16
  const int lg   = lane >> 4;                // 0..3 -> k-group

  f32x4 acc[4][4];
#pragma unroll
  for (int m = 0; m < 4; ++m)
#pragma unroll
    for (int n = 0; n < 4; ++n)
      acc[m][n] = (f32x4){0.f, 0.f, 0.f, 0.f};

#pragma unroll
  for (int ks = 0; ks < 2; ++ks) {
    const int cb = ks * 64 + lg * 16;        // byte col of this lane's 8 bf16
    bf16x8 aH[4], aL[4], bH[4], bL[4];
#pragma unroll
    for (int m = 0; m < 4; ++m) {
      const int row = wr * 64 + m * 16 + lr;
      const int off = row * 128 + (cb ^ ((row & 7) << 4));
      aH[m] = *(const bf16x8*)((const char*)sQh + off);
      aL[m] = *(const bf16x8*)((const char*)sQl + off);
    }
#pragma unroll
    for (int n = 0; n < 4; ++n) {
      const int row = wc * 64 + n * 16 + lr;
      const int off = row * 128 + (cb ^ ((row & 7) << 4));
      bH[n] = *(const bf16x8*)((const char*)sKh + off);
      bL[n] = *(const bf16x8*)((const char*)sKl + off);
    }
    // 3 passes so same-acc MFMAs are 16 apart (dependency spacing)
#pragma unroll
    for (int m = 0; m < 4; ++m)
#pragma unroll
      for (int n = 0; n < 4; ++n)
        acc[m][n] = __builtin_amdgcn_mfma_f32_16x16x32_bf16(aH[m], bH[n], acc[m][n], 0, 0, 0);
#pragma unroll
    for (int m = 0; m < 4; ++m)
#pragma unroll
      for (int n = 0; n < 4; ++n)
        acc[m][n] = __builtin_amdgcn_mfma_f32_16x16x32_bf16(aH[m], bL[n], acc[m][n], 0, 0, 0);
#pragma unroll
    for (int m = 0; m < 4; ++m)
#pragma unroll
      for (int n = 0; n < 4; ++n)
        acc[m][n] = __builtin_amdgcn_mfma_f32_16x16x32_bf16(aL[m], bH[n], acc[m][n], 0, 0, 0);
  }

  // C/D layout: col = lane&15, row = (lane>>4)*4 + reg
  const float scale = 0.125f;
#pragma unroll
  for (int m = 0; m < 4; ++m) {
#pragma unroll
    for (int r = 0; r < 4; ++r) {
      const int i = i0 + wr * 64 + m * 16 + lg * 4 + r;
      float* rowp = attn + ((size_t)bh * kS + i) * kS + j0 + wc * 64 + lr;
#pragma unroll
      for (int n = 0; n < 4; ++n) rowp[n * 16] = acc[m][n][r] * scale;
    }
  }
}

// In-place row softmax over rows of length S=2048. One block per row.
__global__ __launch_bounds__(256) void softmax_kernel(float* __restrict__ attn)
{
  float* p = attn + (size_t)blockIdx.x * kS;
  const int tid = threadIdx.x;

  float4 v0 = ((const float4*)p)[tid];
  float4 v1 = ((const float4*)p)[tid + 256];

  float m = fmaxf(fmaxf(fmaxf(v0.x, v0.y), fmaxf(v0.z, v0.w)),
                  fmaxf(fmaxf(v1.x, v1.y), fmaxf(v1.z, v1.w)));
#pragma unroll
  for (int o = 32; o > 0; o >>= 1) m = fmaxf(m, __shfl_xor(m, o));

  __shared__ float redm[4];
  __shared__ float reds[4];
  const int w = tid >> 6;
  if ((tid & 63) == 0) redm[w] = m;
  __syncthreads();
  m = fmaxf(fmaxf(redm[0], redm[1]), fmaxf(redm[2], redm[3]));

  v0.x = __expf(v0.x - m); v0.y = __expf(v0.y - m);
  v0.z = __expf(v0.z - m); v0.w = __expf(v0.w - m);
  v1.x = __expf(v1.x - m); v1.y = __expf(v1.y - m);
  v1.z = __expf(v1.z - m); v1.w = __expf(v1.w - m);

  float s = v0.x + v0.y + v0.z + v0.w + v1.x + v1.y + v1.z + v1.w;
#pragma unroll
  for (int o = 32; o > 0; o >>= 1) s += __shfl_xor(s, o);
  if ((tid & 63) == 0) reds[w] = s;
  __syncthreads();
  s = reds[0] + reds[1] + reds[2] + reds[3];

  const float inv = 1.0f / s;
  v0.x *= inv; v0.y *= inv; v0.z *= inv; v0.w *= inv;
  v1.x *= inv; v1.y *= inv; v1.z *= inv; v1.w *= inv;
  ((float4*)p)[tid] = v0;
  ((float4*)p)[tid + 256] = v1;
}

// ctx[b][s][h*HD+d] = sum_k P[bh][s][k]*V[bh][k][d], split-bf16 MFMA.
// 128 rows x 64 cols per block, 4 waves each 32x64 (2x4 frags), K-loop over S.
// P (fp32, post-softmax) is split to bf16 hi/lo on the fly during staging.
__global__ __launch_bounds__(256, 2) void pv_mfma(
    const float* __restrict__ attn,
    const unsigned short* __restrict__ Vthi, const unsigned short* __restrict__ Vtlo,
    float* __restrict__ ctx)
{
  __shared__ __align__(16) unsigned short sPh[128 * 64];   // 16 KB, swizzled
  __shared__ __align__(16) unsigned short sPl[128 * 64];
  __shared__ __align__(16) unsigned short sVh[64 * 64];    //  8 KB, swizzled ([d][k])
  __shared__ __align__(16) unsigned short sVl[64 * 64];

  const int tid = threadIdx.x;
  const int i0  = blockIdx.x * 128;
  const int bh  = blockIdx.y;
  const int b   = bh >> 3;
  const int h   = bh & 7;

  const float* Pb = attn + ((size_t)bh * kS + i0) * kS;
  const unsigned short* Vh_ = Vthi + (size_t)bh * kHD * kS;   // [d][s]
  const unsigned short* Vl_ = Vtlo + (size_t)bh * kHD * kS;

  const int wid  = tid >> 6;
  const int lane = tid & 63;
  const int lr   = lane & 15;
  const int lg   = lane >> 4;

  f32x4 acc[2][4];
#pragma unroll
  for (int m = 0; m < 2; ++m)
#pragma unroll
    for (int n = 0; n < 4; ++n)
      acc[m][n] = (f32x4){0.f, 0.f, 0.f, 0.f};

  for (int k0 = 0; k0 < kS; k0 += 64) {
    __syncthreads();                       // previous iter's frag reads done
    // stage P: 128 rows x 64 fp32 = 2048 float4 chunks; 8 per thread
#pragma unroll
    for (int it = 0; it < 8; ++it) {
      const int c   = tid + it * 256;      // 0..2047
      const int row = c >> 4;              // 0..127
      const int f4  = c & 15;              // float4 within row
      float4 p = *(const float4*)(Pb + (size_t)row * kS + k0 + f4 * 4);
      unsigned short h0, l0, h1, l1, h2, l2, h3, l3;
      split_bf16(p.x, h0, l0); split_bf16(p.y, h1, l1);
      split_bf16(p.z, h2, l2); split_bf16(p.w, h3, l3);
      const int bo = (f4 * 8) ^ ((row & 7) << 4);   // 8-B granule, swizzled
      short4v hv = {(short)h0, (short)h1, (short)h2, (short)h3};
      short4v lv = {(short)l0, (short)l1, (short)l2, (short)l3};
      *(short4v*)((char*)sPh + row * 128 + bo) = hv;
      *(short4v*)((char*)sPl + row * 128 + bo) = lv;
    }
    // stage V^T: 64 rows (d) x 64 bf16 (k) per split = 512 x 16B chunks
#pragma unroll
    for (int it = 0; it < 2; ++it) {
      const int c   = tid + it * 256;      // 0..511
      const int row = c >> 3;              // d 0..63
      const int bo  = (c & 7) << 4;
      const int so  = bo ^ ((row & 7) << 4);
      const char* gvh = (const char*)(Vh_ + (size_t)row * kS + k0);
      const char* gvl = (const char*)(Vl_ + (size_t)row * kS + k0);
      *(float4*)((char*)sVh + row * 128 + so) = *(const float4*)(gvh + bo);
      *(float4*)((char*)sVl + row * 128 + so) = *(const float4*)(gvl + bo);
    }
    __syncthreads();

#pragma unroll
    for (int ks = 0; ks < 2; ++ks) {
      const int cb = ks * 64 + lg * 16;
      bf16x8 aH[2], aL[2], bH[4], bL[4];
#pragma unroll
      for (int m = 0; m < 2; ++m) {
        const int row = wid * 32 + m * 16 + lr;
        const int off = row * 128 + (cb ^ ((row & 7) << 4));
        aH[m] = *(const bf16x8*)((const char*)sPh + off);
        aL[m] = *(const bf16x8*)((const char*)sPl + off);
      }
#pragma unroll
      for (int n = 0; n < 4; ++n) {
        const int row = n * 16 + lr;       // d
        const int off = row * 128 + (cb ^ ((row & 7) << 4));
        bH[n] = *(const bf16x8*)((const char*)sVh + off);
        bL[n] = *(const bf16x8*)((const char*)sVl + off);
      }
#pragma unroll
      for (int m = 0; m < 2; ++m)
#pragma unroll
        for (int n = 0; n < 4; ++n)
          acc[m][n] = __builtin_amdgcn_mfma_f32_16x16x32_bf16(aH[m], bH[n], acc[m][n], 0, 0, 0);
#pragma unroll
      for (int m = 0; m < 2; ++m)
#pragma unroll
        for (int n = 0; n < 4; ++n)
          acc[m][n] = __builtin_amdgcn_mfma_f32_16x16x32_bf16(aH[m], bL[n], acc[m][n], 0, 0, 0);
#pragma unroll
      for (int m = 0; m < 2; ++m)
#pragma unroll
        for (int n = 0; n < 4; ++n)
          acc[m][n] = __builtin_amdgcn_mfma_f32_16x16x32_bf16(aL[m], bH[n], acc[m][n], 0, 0, 0);
    }
  }

#pragma unroll
  for (int m = 0; m < 2; ++m) {
#pragma unroll
    for (int r = 0; r < 4; ++r) {
      const int s = i0 + wid * 32 + m * 16 + lg * 4 + r;
      float* rowp = ctx + ((size_t)b * kS + s) * kH + h * kHD + lr;
#pragma unroll
      for (int n = 0; n < 4; ++n) rowp[n * 16] = acc[m][n][r];
    }
  }
}

extern "C" void kernel_launch(void* const* d_in, const int* in_sizes, int n_in,
                              void* d_out, int out_size, void* d_ws,
                              size_t ws_size, hipStream_t stream)
{
  (void)in_sizes; (void)n_in; (void)out_size;

  const float* query  = (const float*)d_in[0];
  const float* key_in = (const float*)d_in[1];
  const float* value  = (const float*)d_in[2];
  const float* Wq = (const float*)d_in[3];
  const float* bq = (const float*)d_in[4];
  const float* Wk = (const float*)d_in[5];
  const float* bk = (const float*)d_in[6];
  const float* Wv = (const float*)d_in[7];
  const float* bv = (const float*)d_in[8];
  const float* Wo = (const float*)d_in[9];
  const float* bo = (const float*)d_in[10];

  float* out  = (float*)d_out;
  float* attn = out + (size_t)kB * kS * kH;   // attention region of d_out

  const size_t headElems = (size_t)kB * kNH * kS * kHD;        // 4,194,304
  // ws: 6 bf16 arrays (Q/K/V hi+lo) + fp32 ctx = 16 B per head element = 64 MB
  if (ws_size < headElems * 16) return;

  unsigned short* Qhi  = (unsigned short*)d_ws;
  unsigned short* Qlo  = Qhi + headElems;
  unsigned short* Khi  = Qlo + headElems;
  unsigned short* Klo  = Khi + headElems;
  unsigned short* Vthi = Klo + headElems;     // transposed [bh][d][s]
  unsigned short* Vtlo = Vthi + headElems;
  float* ctx = (float*)(Vtlo + headElems);

  const dim3 blk(256);
  const dim3 gproj(kM / 64, kH / 64);          // 128 x 8
  gemm_nt_bias<0><<<gproj, blk, 0, stream>>>(query,  Wq, bq, nullptr, Qhi, Qlo);
  gemm_nt_bias<0><<<gproj, blk, 0, stream>>>(key_in, Wk, bk, nullptr, Khi, Klo);
  gemm_nt_bias<2><<<gproj, blk, 0, stream>>>(value,  Wv, bv, nullptr, Vthi, Vtlo);

  const dim3 gsc(kS / 128, kS / 128, kB * kNH);   // 16 x 16 x 32
  scores_mfma<<<gsc, blk, 0, stream>>>(Qhi, Qlo, Khi, Klo, attn);

  softmax_kernel<<<dim3(kB * kNH * kS), blk, 0, stream>>>(attn);

  const dim3 gpv(kS / 128, kB * kNH);             // 16 x 32
  pv_mfma<<<gpv, blk, 0, stream>>>(attn, Vthi, Vtlo, ctx);

  gemm_nt_bias<1><<<gproj, blk, 0, stream>>>(ctx, Wo, bo, out, nullptr, nullptr);
}